// Round 1
// 868.261 us; speedup vs baseline: 2.0294x; 2.0294x over previous
//
#include <hip/hip_runtime.h>
#include <math.h>

#define KDIM   7168
#define NEXP   256
#define NTOK   16384
#define KSTEPS 224          // KDIM / 32

typedef _Float16 half8 __attribute__((ext_vector_type(8)));
typedef _Float16 half4 __attribute__((ext_vector_type(4)));
typedef float    f32x4 __attribute__((ext_vector_type(4)));

// ---------------------------------------------------------------------------
// Prep: split W[k][n] fp32 into (W*1024) = hi + lo f16 planes, stored in
// fragment-linear layout: for K-step ks, n-fragment nf, the 64 lanes' 16B
// B-fragments are contiguous:  hw_off(k,n) = (((ks*16+nf)*4 + kc)*16 + n%16)*8 + k%8
// with kc=(k>>3)&3, so a wave's frag load is base + lane*16B.
// Scale 2^10 keeps lo parts out of f16-denormal flush range.
// ---------------------------------------------------------------------------
__global__ __launch_bounds__(256, 1) void split_w(
    const float* __restrict__ W, _Float16* __restrict__ wh, _Float16* __restrict__ wl)
{
  const int n  = threadIdx.x;        // 0..255
  const int ks = blockIdx.x >> 2;    // 0..223
  const int kc = blockIdx.x & 3;     // 0..3
  const int kb = ks * 32 + kc * 8;
  half8 hv, lv;
#pragma unroll
  for (int i = 0; i < 8; ++i) {
    const float x = W[(size_t)(kb + i) * NEXP + n] * 1024.0f;   // coalesced per i
    const _Float16 h = (_Float16)x;
    hv[i] = h;
    lv[i] = (_Float16)(x - (float)h);
  }
  const size_t o = ((((size_t)ks * 16 + (n >> 4)) * 4 + kc) * 16 + (n & 15)) * 8;
  *(half8*)(wh + o) = hv;
  *(half8*)(wl + o) = lv;
}

// ---------------------------------------------------------------------------
// Fused GEMM (f16 split-3 MFMA, fp32-class accuracy) + routing epilogue.
// Block: 64 tokens x 256 experts, 512 threads (8 waves, each 64x32 cols).
// acc = Ah*Bh + Ah*Bl + Al*Bh   (x,w pre-scaled by 2^10; epilogue * 2^-20)
// A staged per K-step in LDS (fragment-linear, conflict-free b128 reads);
// B frags loaded straight from the L2-resident fragment-linear W planes.
// Epilogue: sigmoid+bias -> swizzled LDS rows -> proven serial routing.
// ---------------------------------------------------------------------------
__global__ __launch_bounds__(512, 2) void gemm_route(
    const float* __restrict__ A,       // [NTOK][KDIM] fp32
    const _Float16* __restrict__ Wh,   // fragment-linear hi plane
    const _Float16* __restrict__ Wl,   // fragment-linear lo plane
    const float* __restrict__ bias,    // [NEXP]
    float* __restrict__ out_idx,       // [NTOK][8]
    float* __restrict__ out_w)         // [NTOK][8]
{
  __shared__ _Float16 a_hi[64 * 32];       // fragment-linear A tile, hi
  __shared__ _Float16 a_lo[64 * 32];       // fragment-linear A tile, lo
  __shared__ float    s_rows[64][256];     // scores, col e stored at e^(row&31)

  const int tid = threadIdx.x;
  const int wv  = tid >> 6;                // wave 0..7 -> cols [wv*32, wv*32+32)
  const int ln  = tid & 63;
  const int m0  = blockIdx.x << 6;

  // A staging: 4 floats per thread (row sm, k offset sk)
  const int sm = tid >> 3;                 // 0..63
  const int sk = (tid & 7) << 2;           // 0,4,...,28
  const float* Ap = A + (size_t)(m0 + sm) * KDIM + sk;
  const int soff = (((sm >> 4) * 4 + (sk >> 3)) * 16 + (sm & 15)) * 8 + (sk & 7);

  // B fragment halfword offsets for this wave's two n-fragments
  const size_t bo0 = (size_t)(wv * 2 + 0) * 512 + (size_t)ln * 8;
  const size_t bo1 = (size_t)(wv * 2 + 1) * 512 + (size_t)ln * 8;

  f32x4 acc[4][2];
#pragma unroll
  for (int i = 0; i < 4; ++i) {
    f32x4 z = {0.f, 0.f, 0.f, 0.f};
    acc[i][0] = z; acc[i][1] = z;
  }

  // prologue prefetch (K-step 0)
  float4 pa  = *(const float4*)Ap;
  half8 nbh0 = *(const half8*)(Wh + bo0);
  half8 nbh1 = *(const half8*)(Wh + bo1);
  half8 nbl0 = *(const half8*)(Wl + bo0);
  half8 nbl1 = *(const half8*)(Wl + bo1);

  for (int ks = 0; ks < KSTEPS; ++ks) {
    // split the prefetched A floats (scale 2^10 exact)
    const float x0 = pa.x * 1024.f, x1 = pa.y * 1024.f,
                x2 = pa.z * 1024.f, x3 = pa.w * 1024.f;
    const _Float16 h0 = (_Float16)x0, h1 = (_Float16)x1,
                   h2 = (_Float16)x2, h3 = (_Float16)x3;
    half4 hv = {h0, h1, h2, h3};
    half4 lv = {(_Float16)(x0 - (float)h0), (_Float16)(x1 - (float)h1),
                (_Float16)(x2 - (float)h2), (_Float16)(x3 - (float)h3)};

    __syncthreads();                       // prior reads of a_hi/a_lo done
    *(half4*)(&a_hi[soff]) = hv;
    *(half4*)(&a_lo[soff]) = lv;
    __syncthreads();                       // tile visible

    const half8 bh0 = nbh0, bh1 = nbh1, bl0 = nbl0, bl1 = nbl1;
    if (ks + 1 < KSTEPS) {                 // prefetch next K-step
      pa = *(const float4*)(Ap + (size_t)(ks + 1) * 32);
      const size_t adv = (size_t)(ks + 1) * 8192;
      nbh0 = *(const half8*)(Wh + adv + bo0);
      nbh1 = *(const half8*)(Wh + adv + bo1);
      nbl0 = *(const half8*)(Wl + adv + bo0);
      nbl1 = *(const half8*)(Wl + adv + bo1);
    }

#pragma unroll
    for (int mf = 0; mf < 4; ++mf) {
      const half8 ah = *(const half8*)(&a_hi[mf * 512 + ln * 8]);  // linear 1KB/wave
      const half8 al = *(const half8*)(&a_lo[mf * 512 + ln * 8]);
      acc[mf][0] = __builtin_amdgcn_mfma_f32_16x16x32_f16(ah, bh0, acc[mf][0], 0, 0, 0);
      acc[mf][1] = __builtin_amdgcn_mfma_f32_16x16x32_f16(ah, bh1, acc[mf][1], 0, 0, 0);
      acc[mf][0] = __builtin_amdgcn_mfma_f32_16x16x32_f16(ah, bl0, acc[mf][0], 0, 0, 0);
      acc[mf][1] = __builtin_amdgcn_mfma_f32_16x16x32_f16(ah, bl1, acc[mf][1], 0, 0, 0);
      acc[mf][0] = __builtin_amdgcn_mfma_f32_16x16x32_f16(al, bh0, acc[mf][0], 0, 0, 0);
      acc[mf][1] = __builtin_amdgcn_mfma_f32_16x16x32_f16(al, bh1, acc[mf][1], 0, 0, 0);
    }
  }

  // ---- epilogue: scores_for_choice = sigmoid(logit) + bias, swizzled LDS ----
  const int   fq = ln >> 4, fr = ln & 15;
  const float b0 = bias[wv * 32 + fr];
  const float b1 = bias[wv * 32 + 16 + fr];
  const float SC = 1.0f / 1048576.0f;      // 2^-20 (undo both 2^10 scalings)
#pragma unroll
  for (int mf = 0; mf < 4; ++mf) {
#pragma unroll
    for (int j = 0; j < 4; ++j) {
      const int row = mf * 16 + fq * 4 + j;
      const int c0  = wv * 32 + fr;
      const int c1  = c0 + 16;
      s_rows[row][c0 ^ (row & 31)] = 1.0f / (1.0f + expf(-acc[mf][0][j] * SC)) + b0;
      s_rows[row][c1 ^ (row & 31)] = 1.0f / (1.0f + expf(-acc[mf][1][j] * SC)) + b1;
    }
  }
  __syncthreads();

  // ---- routing (identical, already-verified algorithm; 1 thread = 1 token) ----
  if (tid < 64) {
    const int sw = tid & 31;
    const float* row = &s_rows[tid][0];
#define RD(e) row[(e) ^ sw]
    float gs[8];
#pragma unroll
    for (int g = 0; g < 8; ++g) {
      float m1 = -3.0e38f, m2 = -3.0e38f;
#pragma unroll
      for (int e = 0; e < 32; ++e) {
        const float v = RD(g * 32 + e);
        if (v > m1) { m2 = m1; m1 = v; }
        else if (v > m2) { m2 = v; }
      }
      gs[g] = m1 + m2;
    }

    int selmask = 0;
#pragma unroll
    for (int k = 0; k < 4; ++k) {
      float best = -3.0e38f; int bg = 0;
#pragma unroll
      for (int g = 0; g < 8; ++g)
        if (!((selmask >> g) & 1) && gs[g] > best) { best = gs[g]; bg = g; }
      selmask |= (1 << bg);
    }

    float tv[8]; int ti[8];
#pragma unroll
    for (int i = 0; i < 8; ++i) { tv[i] = -3.0e38f; ti[i] = 0; }
#pragma unroll 4
    for (int e = 0; e < 256; ++e) {
      const bool sel = (selmask >> (e >> 5)) & 1;
      const float v = sel ? RD(e) : 0.0f;
      if (v > tv[7]) {
        tv[7] = v; ti[7] = e;
#pragma unroll
        for (int p = 7; p > 0; --p) {
          if (tv[p] > tv[p - 1]) {
            const float tf = tv[p]; tv[p] = tv[p - 1]; tv[p - 1] = tf;
            const int   tt = ti[p]; ti[p] = ti[p - 1]; ti[p - 1] = tt;
          }
        }
      }
    }

    float w8[8], denom = 0.f;
#pragma unroll
    for (int i = 0; i < 8; ++i) { w8[i] = RD(ti[i]); denom += w8[i]; }
    denom += 1e-20f;

    const size_t t = (size_t)m0 + tid;
#pragma unroll
    for (int i = 0; i < 8; ++i) {
      out_idx[t * 8 + i] = (float)ti[i];
      out_w[t * 8 + i]   = (w8[i] / denom) * 2.5f;
    }
#undef RD
  }
}

// ---------------------------------------------------------------------------
extern "C" void kernel_launch(void* const* d_in, const int* in_sizes, int n_in,
                              void* d_out, int out_size, void* d_ws, size_t ws_size,
                              hipStream_t stream)
{
  const float* hs   = (const float*)d_in[0];   // [4,4096,7168] fp32
  const float* w    = (const float*)d_in[1];   // [7168,256]    fp32
  const float* bias = (const float*)d_in[2];   // [256]         fp32
  float* out = (float*)d_out;                  // [16384*8 idx][16384*8 w]

  _Float16* wh = (_Float16*)d_ws;              // 3.67 MB
  _Float16* wl = wh + (size_t)KDIM * NEXP;     // 3.67 MB (ws >= 16 MiB)

  split_w<<<KSTEPS * 4, 256, 0, stream>>>(w, wh, wl);
  gemm_route<<<NTOK / 64, 512, 0, stream>>>(hs, wh, wl, bias, out, out + (size_t)NTOK * 8);
}

// Round 4
// 856.053 us; speedup vs baseline: 2.0583x; 1.0143x over previous
//
#include <hip/hip_runtime.h>
#include <math.h>

#define KDIM   7168
#define NEXP   256
#define NTOK   16384
#define BM     32
#define BK     128
#define NIT    (KDIM / BK)   // 56 iterations, 4 MFMA k-steps each

typedef _Float16 half8 __attribute__((ext_vector_type(8)));
typedef float    f32x4 __attribute__((ext_vector_type(4)));

// ---------------------------------------------------------------------------
// Prep: split W[k][n] fp32 into (W*1024) = hi + lo f16 planes, fragment-linear:
// hw_off(k,n) = (((ks*16+nf)*4 + kc)*16 + n%16)*8 + k%8,  kc=(k>>3)&3.
// A wave's 16B B-fragment load is base + lane*16B (one dwordx4 / lane).
// (Unchanged from round 1 — ran and passed on hardware.)
// ---------------------------------------------------------------------------
__global__ __launch_bounds__(256, 1) void split_w(
    const float* __restrict__ W, _Float16* __restrict__ wh, _Float16* __restrict__ wl)
{
  const int n  = threadIdx.x;        // 0..255
  const int ks = blockIdx.x >> 2;    // 0..223
  const int kc = blockIdx.x & 3;     // 0..3
  const int kb = ks * 32 + kc * 8;
  half8 hv, lv;
#pragma unroll
  for (int i = 0; i < 8; ++i) {
    const float x = W[(size_t)(kb + i) * NEXP + n] * 1024.0f;
    const _Float16 h = (_Float16)x;
    hv[i] = h;
    lv[i] = (_Float16)(x - (float)h);
  }
  const size_t o = ((((size_t)ks * 16 + (n >> 4)) * 4 + kc) * 16 + (n & 15)) * 8;
  *(half8*)(wh + o) = hv;
  *(half8*)(wl + o) = lv;
}

// ---------------------------------------------------------------------------
// Fused GEMM (f16 split-3 MFMA) + routing. BM=32 tokens/block, grid 512
// (2 blocks/CU @ 32KB LDS, 4 waves/SIMD). NO inline asm: plain __syncthreads,
// barrier cost amortized by BK=128 (2 barriers per 48 MFMA/wave).
// Staging: thread t writes one half8 per plane at a[plane][t*8] -> fully
// linear ds_write_b128, conflict-free. A prefetched into regs one iteration
// ahead (full compute phase of slack covers HBM latency).
// Accumulation chain order bitwise-identical to the round-1 PASSING kernel.
// ---------------------------------------------------------------------------
#define MFMA  __builtin_amdgcn_mfma_f32_16x16x32_f16

__global__ __launch_bounds__(512, 4) void gemm_route(
    const float* __restrict__ A,       // [NTOK][KDIM] fp32
    const _Float16* __restrict__ Wh,   // fragment-linear hi plane
    const _Float16* __restrict__ Wl,   // fragment-linear lo plane
    const float* __restrict__ bias,    // [NEXP]
    float* __restrict__ out_idx,       // [NTOK][8]
    float* __restrict__ out_w)         // [NTOK][8]
{
  __shared__ union {
    _Float16 a[2][BM * BK];            // [plane][4 k-steps x 1024 frag-linear]
    float    rows[BM][256];            // epilogue scores (col e at e^(row&31))
  } sm;                                // 32 KB

  const int tid = threadIdx.x;
  const int wv  = tid >> 6;            // 0..7 -> expert cols wv*32..+31
  const int ln  = tid & 63;
  const int m0  = blockIdx.x * BM;

  // --- A staging: thread t = chunk (ksl, mgrp, kc, m15) -> 8 consecutive k ---
  const int srow = (((tid >> 6) & 1) << 4) | (tid & 15);          // 0..31
  const int skol = ((tid >> 7) << 5) | (((tid >> 4) & 3) << 3);   // 0..120
  const float* Ap = A + (size_t)(m0 + srow) * KDIM + skol;

  // --- B fragment pointers (per-wave, fragment-linear planes) ---
  const int boff = wv * 1024 + ln * 8;               // halfs; nf1 adds 512
  const _Float16* Bh = Wh + boff;
  const _Float16* Bl = Wl + boff;

  f32x4 acc00 = {0.f, 0.f, 0.f, 0.f}, acc01 = acc00, acc10 = acc00, acc11 = acc00;

  // prologue: prefetch iteration 0's A chunk (8 floats/thread)
  float4 pa0 = *(const float4*)(Ap);
  float4 pa1 = *(const float4*)(Ap + 4);

  for (int it = 0; it < NIT; ++it) {
    __syncthreads();                   // prior compute's reads of sm.a done
    {                                  // split (scale 2^10 exact) & commit
      float xx[8] = {pa0.x, pa0.y, pa0.z, pa0.w, pa1.x, pa1.y, pa1.z, pa1.w};
      half8 hv, lv;
#pragma unroll
      for (int q = 0; q < 8; ++q) {
        const float xs = xx[q] * 1024.0f;
        const _Float16 hh = (_Float16)xs;
        hv[q] = hh;
        lv[q] = (_Float16)(xs - (float)hh);
      }
      *(half8*)&sm.a[0][tid * 8] = hv;   // linear 16B/thread: conflict-free
      *(half8*)&sm.a[1][tid * 8] = lv;
    }
    __syncthreads();                   // tile visible

    if (it + 1 < NIT) {                // prefetch next iteration's A chunk
      pa0 = *(const float4*)(Ap + (size_t)(it + 1) * BK);
      pa1 = *(const float4*)(Ap + (size_t)(it + 1) * BK + 4);
    }

#pragma unroll
    for (int s = 0; s < 4; ++s) {      // 4 k-steps of 32; chain == round 1
      const int kadv = (it * 4 + s) * 8192;
      const half8 bh0 = *(const half8*)(Bh + kadv);
      const half8 bh1 = *(const half8*)(Bh + kadv + 512);
      const half8 bl0 = *(const half8*)(Bl + kadv);
      const half8 bl1 = *(const half8*)(Bl + kadv + 512);
      const half8 ah0 = *(const half8*)&sm.a[0][s * 1024 + ln * 8];
      const half8 ah1 = *(const half8*)&sm.a[0][s * 1024 + 512 + ln * 8];
      const half8 al0 = *(const half8*)&sm.a[1][s * 1024 + ln * 8];
      const half8 al1 = *(const half8*)&sm.a[1][s * 1024 + 512 + ln * 8];
      acc00 = MFMA(ah0, bh0, acc00, 0, 0, 0);
      acc01 = MFMA(ah0, bh1, acc01, 0, 0, 0);
      acc10 = MFMA(ah1, bh0, acc10, 0, 0, 0);
      acc11 = MFMA(ah1, bh1, acc11, 0, 0, 0);
      acc00 = MFMA(ah0, bl0, acc00, 0, 0, 0);
      acc01 = MFMA(ah0, bl1, acc01, 0, 0, 0);
      acc10 = MFMA(ah1, bl0, acc10, 0, 0, 0);
      acc11 = MFMA(ah1, bl1, acc11, 0, 0, 0);
      acc00 = MFMA(al0, bh0, acc00, 0, 0, 0);
      acc01 = MFMA(al0, bh1, acc01, 0, 0, 0);
      acc10 = MFMA(al1, bh0, acc10, 0, 0, 0);
      acc11 = MFMA(al1, bh1, acc11, 0, 0, 0);
    }
  }

  // ---- epilogue: sigmoid+bias into swizzled LDS rows (union reuse) ----
  __syncthreads();                     // all LDS reads of a[] done
  const int   fq = ln >> 4, fr = ln & 15;
  const float b0v = bias[wv * 32 + fr];
  const float b1v = bias[wv * 32 + 16 + fr];
  const float SC  = 1.0f / 1048576.0f; // 2^-20 (undo both 2^10 scalings)
  const int   c0  = wv * 32 + fr, c1 = c0 + 16;
#pragma unroll
  for (int j = 0; j < 4; ++j) {
    const int r0 = fq * 4 + j;         // rows 0..15  (acc*0)
    const int r1 = 16 + fq * 4 + j;    // rows 16..31 (acc*1)
    sm.rows[r0][c0 ^ (r0 & 31)] = 1.0f / (1.0f + expf(-acc00[j] * SC)) + b0v;
    sm.rows[r0][c1 ^ (r0 & 31)] = 1.0f / (1.0f + expf(-acc01[j] * SC)) + b1v;
    sm.rows[r1][c0 ^ (r1 & 31)] = 1.0f / (1.0f + expf(-acc10[j] * SC)) + b0v;
    sm.rows[r1][c1 ^ (r1 & 31)] = 1.0f / (1.0f + expf(-acc11[j] * SC)) + b1v;
  }
  __syncthreads();

  // ---- routing (verified serial algorithm, 1 thread = 1 token) ----
  if (tid < 32) {
    const int sw = tid & 31;
    const float* row = &sm.rows[tid][0];
#define RD(e) row[(e) ^ sw]
    float gs[8];
#pragma unroll
    for (int g = 0; g < 8; ++g) {
      float m1 = -3.0e38f, m2 = -3.0e38f;
#pragma unroll
      for (int e = 0; e < 32; ++e) {
        const float v = RD(g * 32 + e);
        if (v > m1) { m2 = m1; m1 = v; }
        else if (v > m2) { m2 = v; }
      }
      gs[g] = m1 + m2;
    }

    int selmask = 0;
#pragma unroll
    for (int k = 0; k < 4; ++k) {
      float best = -3.0e38f; int bg = 0;
#pragma unroll
      for (int g = 0; g < 8; ++g)
        if (!((selmask >> g) & 1) && gs[g] > best) { best = gs[g]; bg = g; }
      selmask |= (1 << bg);
    }

    float tv[8]; int ti[8];
#pragma unroll
    for (int i = 0; i < 8; ++i) { tv[i] = -3.0e38f; ti[i] = 0; }
#pragma unroll 4
    for (int e = 0; e < 256; ++e) {
      const bool sel = (selmask >> (e >> 5)) & 1;
      const float v = sel ? RD(e) : 0.0f;
      if (v > tv[7]) {
        tv[7] = v; ti[7] = e;
#pragma unroll
        for (int p = 7; p > 0; --p) {
          if (tv[p] > tv[p - 1]) {
            const float tf = tv[p]; tv[p] = tv[p - 1]; tv[p - 1] = tf;
            const int   tt = ti[p]; ti[p] = ti[p - 1]; ti[p - 1] = tt;
          }
        }
      }
    }

    float w8[8], denom = 0.f;
#pragma unroll
    for (int i = 0; i < 8; ++i) { w8[i] = RD(ti[i]); denom += w8[i]; }
    denom += 1e-20f;

    const size_t t = (size_t)m0 + tid;
#pragma unroll
    for (int i = 0; i < 8; ++i) {
      out_idx[t * 8 + i] = (float)ti[i];
      out_w[t * 8 + i]   = (w8[i] / denom) * 2.5f;
    }
#undef RD
  }
}

// ---------------------------------------------------------------------------
extern "C" void kernel_launch(void* const* d_in, const int* in_sizes, int n_in,
                              void* d_out, int out_size, void* d_ws, size_t ws_size,
                              hipStream_t stream)
{
  const float* hs   = (const float*)d_in[0];   // [4,4096,7168] fp32
  const float* w    = (const float*)d_in[1];   // [7168,256]    fp32
  const float* bias = (const float*)d_in[2];   // [256]         fp32
  float* out = (float*)d_out;                  // [16384*8 idx][16384*8 w]

  _Float16* wh = (_Float16*)d_ws;              // 3.67 MB
  _Float16* wl = wh + (size_t)KDIM * NEXP;     // 3.67 MB

  split_w<<<896, 256, 0, stream>>>(w, wh, wl);
  gemm_route<<<NTOK / BM, 512, 0, stream>>>(hs, wh, wl, bias, out, out + (size_t)NTOK * 8);
}